// Round 1
// baseline (1527.732 us; speedup 1.0000x reference)
//
#include <hip/hip_runtime.h>

#define D 4096
#define CSTRIDE 2016   // codes per row: 16 * (2+4+8+16+32+64)
#define AS_STRIDE 164  // 160 K-rows + pad, keeps 16B alignment & breaks conflicts

// -------------------- Kernel 1: rank-16 codes ------------------------------
// codes[t][offt_i + j*16 + r] = sum_k x[t, j*s+k] * us[i][j][k][r]
// WG = 16 rows, 256 threads = (row a 0..15) x (rank b 0..15).
// K processed in 512-col chunks; layers 0..2 (s>=512) carry accumulators
// across chunks, layers 3..5 flush per sub-block.
__global__ __launch_bounds__(256, 2) void hodlr_codes(
    const float* __restrict__ x,
    const float* __restrict__ us0, const float* __restrict__ us1,
    const float* __restrict__ us2, const float* __restrict__ us3,
    const float* __restrict__ us4, const float* __restrict__ us5,
    float* __restrict__ codes)
{
    __shared__ float xs[16 * 520];    // 16 rows x 512, stride 520 (bank pad)
    __shared__ float uss[512 * 16];   // us slice for current chunk/layer

    const int t0 = blockIdx.x * 16;
    const int a = threadIdx.x >> 4;   // row
    const int b = threadIdx.x & 15;   // rank

    float accp0 = 0.f, accp1 = 0.f, accp2 = 0.f;
    const float* usp[6] = {us0, us1, us2, us3, us4, us5};

    for (int c = 0; c < 8; ++c) {
        const int base = c << 9;
        __syncthreads();  // previous chunk's compute done reading xs
        for (int idx = threadIdx.x; idx < 16 * 128; idx += 256) {
            const int r = idx >> 7, c4 = idx & 127;
            *(float4*)(xs + r * 520 + c4 * 4) =
                *(const float4*)(x + (size_t)(t0 + r) * D + base + c4 * 4);
        }
        #pragma unroll
        for (int i = 0; i < 6; ++i) {
            const int s = D >> (i + 1);
            const int offt = 16 * ((2 << i) - 2);
            __syncthreads();  // prev layer done reading uss (covers xs staged for i=0)
            {
                const float* up = usp[i] + (size_t)base * 16;  // us flat addr = k_global*16+r
                for (int idx = threadIdx.x; idx < 2048; idx += 256)
                    *(float4*)(uss + idx * 4) = *(const float4*)(up + idx * 4);
            }
            __syncthreads();
            const int klen = (s >= 512) ? 512 : s;
            const int nsub = 512 / klen;
            for (int sub = 0; sub < nsub; ++sub) {
                float acc = (i == 0) ? accp0 : (i == 1) ? accp1 : (i == 2) ? accp2 : 0.f;
                const int kb = sub * klen;
                for (int k = 0; k < klen; k += 4) {
                    const float4 xv = *(const float4*)(xs + a * 520 + kb + k);
                    acc = fmaf(xv.x, uss[(kb + k + 0) * 16 + b], acc);
                    acc = fmaf(xv.y, uss[(kb + k + 1) * 16 + b], acc);
                    acc = fmaf(xv.z, uss[(kb + k + 2) * 16 + b], acc);
                    acc = fmaf(xv.w, uss[(kb + k + 3) * 16 + b], acc);
                }
                if (i <= 2) {
                    if (((base + 512) & (s - 1)) == 0) {  // block boundary reached
                        const int j = base / s;
                        codes[(size_t)(t0 + a) * CSTRIDE + offt + j * 16 + b] = acc;
                        acc = 0.f;
                    }
                    if (i == 0) accp0 = acc; else if (i == 1) accp1 = acc; else accp2 = acc;
                } else {
                    const int j = (base + kb) / s;
                    codes[(size_t)(t0 + a) * CSTRIDE + offt + j * 16 + b] = acc;
                }
            }
        }
    }
}

// -------------------- Kernel 2: output GEMMs -------------------------------
// out chunk b (64 cols) for 64 rows: A(64x160) = [x_chunk | codes(6x16)],
// W(160x64) = [ds[b] ; vs[i][sib][:, local*64:+64] for i=0..5], + bias.
// W staged in two 80-row halves to keep LDS at 62.5 KB (2 WGs/CU).
__global__ __launch_bounds__(256, 2) void hodlr_out(
    const float* __restrict__ x,
    const float* __restrict__ vs0, const float* __restrict__ vs1,
    const float* __restrict__ vs2, const float* __restrict__ vs3,
    const float* __restrict__ vs4, const float* __restrict__ vs5,
    const float* __restrict__ dsm, const float* __restrict__ bias,
    const float* __restrict__ codes,
    float* __restrict__ out)
{
    __shared__ float As[64 * AS_STRIDE];  // [row][k], 41.98 KB
    __shared__ float Ws[80 * 64];         // [k_local][col], 20.48 KB

    const int bch = blockIdx.x;           // output chunk 0..63
    const int t0  = blockIdx.y * 64;
    const int tid = threadIdx.x;
    const int tr = tid >> 4, tc = tid & 15;  // 4x4 output tile per thread

    // ---- stage A: x part (k = 0..63)
    for (int idx = tid; idx < 64 * 16; idx += 256) {
        const int row = idx >> 4, c4 = idx & 15;
        *(float4*)(As + row * AS_STRIDE + c4 * 4) =
            *(const float4*)(x + (size_t)(t0 + row) * D + bch * 64 + c4 * 4);
    }
    // ---- stage A: codes part (k = 64..159); cbase computed arithmetically
    for (int idx = tid; idx < 64 * 24; idx += 256) {
        const int row = idx / 24, q4 = idx - row * 24;
        const int i = q4 >> 2, r4 = q4 & 3;
        const int offt = 32 * ((1 << i) - 1);
        const int sib = ((bch >> (5 - i)) ^ 1);
        *(float4*)(As + row * AS_STRIDE + 64 + q4 * 4) =
            *(const float4*)(codes + (size_t)(t0 + row) * CSTRIDE + offt + sib * 16 + r4 * 4);
    }

    float acc[4][4];
    #pragma unroll
    for (int e = 0; e < 4; ++e)
        #pragma unroll
        for (int f = 0; f < 4; ++f) acc[e][f] = 0.f;

    const float* vsp[5] = {vs1, vs2, vs3, vs4, vs5};

    #pragma unroll
    for (int h = 0; h < 2; ++h) {
        __syncthreads();  // h=0: nothing to protect yet; h=1: done reading Ws half 0
        if (h == 0) {
            // ds[b]: k rows 0..63
            for (int idx = tid; idx < 64 * 16; idx += 256) {
                const int kk = idx >> 4, c4 = (idx & 15) << 2;
                *(float4*)(Ws + kk * 64 + c4) =
                    *(const float4*)(dsm + (size_t)bch * 4096 + kk * 64 + c4);
            }
            // layer 0: k rows 64..79 (local 64..79)
            {
                const int r = tid >> 4, c4 = (tid & 15) << 2;
                const int sib = (bch >> 5) ^ 1, loc = bch & 31;
                *(float4*)(Ws + (64 + r) * 64 + c4) =
                    *(const float4*)(vs0 + (size_t)sib * 16 * 2048 + r * 2048 + loc * 64 + c4);
            }
        } else {
            // layers 1..5: k rows 80..159 (local 0..79)
            #pragma unroll
            for (int i = 1; i <= 5; ++i) {
                const int s = D >> (i + 1);
                const int r = tid >> 4, c4 = (tid & 15) << 2;
                const int sib = (bch >> (5 - i)) ^ 1;
                const int loc = bch & ((1 << (5 - i)) - 1);
                *(float4*)(Ws + ((i - 1) * 16 + r) * 64 + c4) =
                    *(const float4*)(vsp[i - 1] + (size_t)sib * 16 * s + r * s + loc * 64 + c4);
            }
        }
        __syncthreads();  // Ws (and As on h=0) visible

        const int kbase = h * 80;
        #pragma unroll 4
        for (int kk = 0; kk < 80; kk += 4) {
            const int kg = kbase + kk;
            const float4 a0 = *(const float4*)(As + (tr * 4 + 0) * AS_STRIDE + kg);
            const float4 a1 = *(const float4*)(As + (tr * 4 + 1) * AS_STRIDE + kg);
            const float4 a2 = *(const float4*)(As + (tr * 4 + 2) * AS_STRIDE + kg);
            const float4 a3 = *(const float4*)(As + (tr * 4 + 3) * AS_STRIDE + kg);
            const float4 w0 = *(const float4*)(Ws + (kk + 0) * 64 + tc * 4);
            const float4 w1 = *(const float4*)(Ws + (kk + 1) * 64 + tc * 4);
            const float4 w2 = *(const float4*)(Ws + (kk + 2) * 64 + tc * 4);
            const float4 w3 = *(const float4*)(Ws + (kk + 3) * 64 + tc * 4);
#define ROWK(e, A, W) \
            acc[e][0] = fmaf(A, W.x, acc[e][0]); \
            acc[e][1] = fmaf(A, W.y, acc[e][1]); \
            acc[e][2] = fmaf(A, W.z, acc[e][2]); \
            acc[e][3] = fmaf(A, W.w, acc[e][3]);
            ROWK(0, a0.x, w0) ROWK(0, a0.y, w1) ROWK(0, a0.z, w2) ROWK(0, a0.w, w3)
            ROWK(1, a1.x, w0) ROWK(1, a1.y, w1) ROWK(1, a1.z, w2) ROWK(1, a1.w, w3)
            ROWK(2, a2.x, w0) ROWK(2, a2.y, w1) ROWK(2, a2.z, w2) ROWK(2, a2.w, w3)
            ROWK(3, a3.x, w0) ROWK(3, a3.y, w1) ROWK(3, a3.z, w2) ROWK(3, a3.w, w3)
#undef ROWK
        }
    }

    const float4 bv = *(const float4*)(bias + bch * 64 + tc * 4);
    #pragma unroll
    for (int e = 0; e < 4; ++e) {
        float4 o;
        o.x = acc[e][0] + bv.x;
        o.y = acc[e][1] + bv.y;
        o.z = acc[e][2] + bv.z;
        o.w = acc[e][3] + bv.w;
        *(float4*)(out + (size_t)(t0 + tr * 4 + e) * D + bch * 64 + tc * 4) = o;
    }
}

// -------------------- launch ----------------------------------------------
extern "C" void kernel_launch(void* const* d_in, const int* in_sizes, int n_in,
                              void* d_out, int out_size, void* d_ws, size_t ws_size,
                              hipStream_t stream)
{
    // setup_inputs() dict order: x, us0, vs0, us1, vs1, ..., us5, vs5, ds, bias
    const float* x   = (const float*)d_in[0];
    const float* us0 = (const float*)d_in[1];
    const float* vs0 = (const float*)d_in[2];
    const float* us1 = (const float*)d_in[3];
    const float* vs1 = (const float*)d_in[4];
    const float* us2 = (const float*)d_in[5];
    const float* vs2 = (const float*)d_in[6];
    const float* us3 = (const float*)d_in[7];
    const float* vs3 = (const float*)d_in[8];
    const float* us4 = (const float*)d_in[9];
    const float* vs4 = (const float*)d_in[10];
    const float* us5 = (const float*)d_in[11];
    const float* vs5 = (const float*)d_in[12];
    const float* dsm = (const float*)d_in[13];
    const float* bias= (const float*)d_in[14];
    float* out   = (float*)d_out;
    float* codes = (float*)d_ws;  // 16384 * 2016 * 4B = 132 MB scratch

    const int T = in_sizes[0] / D;  // 16384 rows

    hipLaunchKernelGGL(hodlr_codes, dim3(T / 16), dim3(256), 0, stream,
                       x, us0, us1, us2, us3, us4, us5, codes);
    hipLaunchKernelGGL(hodlr_out, dim3(64, T / 64), dim3(256), 0, stream,
                       x, vs0, vs1, vs2, vs3, vs4, vs5, dsm, bias, codes, out);
}

// Round 2
// 629.566 us; speedup vs baseline: 2.4266x; 2.4266x over previous
//
#include <hip/hip_runtime.h>

#define D 4096
#define CSTRIDE 2016   // codes per row: 16*(2+4+8+16+32+64); offsets {0,32,96,224,480,992}

typedef unsigned short u16;
typedef __bf16 bf16x8 __attribute__((ext_vector_type(8)));
typedef u16    u16x8  __attribute__((ext_vector_type(8)));
typedef u16    u16x4v __attribute__((ext_vector_type(4)));
typedef float  f32x4  __attribute__((ext_vector_type(4)));

__device__ __forceinline__ u16 f2bf(float f) {   // RNE float->bf16 (finite inputs)
    unsigned u = __float_as_uint(f);
    u += 0x7fffu + ((u >> 16) & 1u);
    return (u16)(u >> 16);
}

// -------------------- Kernel 0: weight prep (bf16 transposes) ---------------
// usT[i][(j*16+r)*s + k] = us[i][j][k][r]          (6 * 65536 elements)
// WT[b][n*160 + k]: k<64 -> ds[b][k][n]; k=64+i*16+r -> vs[i][sib][r][loc*64+n]
__global__ __launch_bounds__(256) void hodlr_prep(
    const float* __restrict__ us0, const float* __restrict__ us1,
    const float* __restrict__ us2, const float* __restrict__ us3,
    const float* __restrict__ us4, const float* __restrict__ us5,
    const float* __restrict__ vs0, const float* __restrict__ vs1,
    const float* __restrict__ vs2, const float* __restrict__ vs3,
    const float* __restrict__ vs4, const float* __restrict__ vs5,
    const float* __restrict__ dsm,
    u16* __restrict__ usT, u16* __restrict__ WT)
{
    const float* usp[6] = {us0, us1, us2, us3, us4, us5};
    const float* vsp[6] = {vs0, vs1, vs2, vs3, vs4, vs5};
    const int idx = blockIdx.x * 256 + threadIdx.x;
    if (idx < 6 * 65536) {
        const int i = idx >> 16, rem = idx & 65535;
        const int lg = 11 - i, s = 2048 >> i;
        const int jr = rem >> lg, k = rem & (s - 1);
        const int j = jr >> 4, r = jr & 15;
        usT[idx] = f2bf(usp[i][(size_t)(j * s + k) * 16 + r]);
    } else if (idx < 6 * 65536 + 64 * 10240) {
        const int w = idx - 6 * 65536;
        const int b = w / 10240, rem = w - b * 10240;
        const int n = rem / 160, k = rem - n * 160;
        float val;
        if (k < 64) {
            val = dsm[b * 4096 + k * 64 + n];
        } else {
            const int i = (k - 64) >> 4, r = (k - 64) & 15;
            const int s = 2048 >> i;
            const int sib = (b >> (5 - i)) ^ 1;
            const int loc = b & ((1 << (5 - i)) - 1);
            val = vsp[i][(size_t)sib * 16 * s + r * s + loc * 64 + n];
        }
        WT[w] = f2bf(val);
    }
}

// -------------------- Kernel 1: rank-16 codes via MFMA ----------------------
// Grid (T/64, 2): 64 rows/WG (4 waves x 16), K-half of 2048 cols per WG.
// Per 64-col chunk: A-frags straight from global x (fp32->bf16 in regs),
// usT slices for all 6 layers staged in LDS; 12 MFMAs; flush per-layer
// accumulators (bf16) at block boundaries. No cross-WG accumulation:
// 2048 is a multiple of every layer block size.
__global__ __launch_bounds__(256) void hodlr_codes(
    const float* __restrict__ x, const u16* __restrict__ usT,
    u16* __restrict__ codes)
{
    __shared__ __align__(16) u16 uss[6 * 16 * 72];   // [layer][rank][72], 13.8 KB

    const int tid = threadIdx.x, lane = tid & 63, wv = tid >> 6;
    const int m = lane & 15, quad = lane >> 4;
    const int t0 = blockIdx.x * 64;
    const int kbase = blockIdx.y * 2048;
    const float* xrow = x + (size_t)(t0 + wv * 16 + m) * D;

    f32x4 acc[6];
    #pragma unroll
    for (int i = 0; i < 6; ++i) acc[i] = (f32x4){0.f, 0.f, 0.f, 0.f};

    for (int c = 0; c < 32; ++c) {
        const int kb = kbase + c * 64;
        __syncthreads();   // previous chunk's B-frag readers done with uss
        // A: 64 cols of this lane's row (k = quad*8 + e within each 32-step)
        const float4 xv0 = *(const float4*)(xrow + kb + quad * 8);
        const float4 xv1 = *(const float4*)(xrow + kb + quad * 8 + 4);
        const float4 xv2 = *(const float4*)(xrow + kb + 32 + quad * 8);
        const float4 xv3 = *(const float4*)(xrow + kb + 32 + quad * 8 + 4);
        // stage usT slices: 6 layers x 16 ranks x 64 k (bf16), 3 x b128/thread
        #pragma unroll
        for (int p = 0; p < 3; ++p) {
            const int u = tid + p * 256;            // 0..767
            const int i = u >> 7, rem = u & 127, r = rem >> 3, seg = rem & 7;
            const int lg = 11 - i;
            const int j = kb >> lg;
            const int koff = kb & ((2048 >> i) - 1);
            const size_t src = ((size_t)i << 16) + ((size_t)((j << 4) + r) << lg)
                             + koff + (seg << 3);
            *(float4*)&uss[(i * 16 + r) * 72 + (seg << 3)] =
                *(const float4*)(usT + src);
        }
        __syncthreads();

        union { u16x8 u; bf16x8 v; } a0, a1;
        a0.u[0] = f2bf(xv0.x); a0.u[1] = f2bf(xv0.y); a0.u[2] = f2bf(xv0.z); a0.u[3] = f2bf(xv0.w);
        a0.u[4] = f2bf(xv1.x); a0.u[5] = f2bf(xv1.y); a0.u[6] = f2bf(xv1.z); a0.u[7] = f2bf(xv1.w);
        a1.u[0] = f2bf(xv2.x); a1.u[1] = f2bf(xv2.y); a1.u[2] = f2bf(xv2.z); a1.u[3] = f2bf(xv2.w);
        a1.u[4] = f2bf(xv3.x); a1.u[5] = f2bf(xv3.y); a1.u[6] = f2bf(xv3.z); a1.u[7] = f2bf(xv3.w);

        #pragma unroll
        for (int i = 0; i < 6; ++i) {
            const u16* bp = &uss[(i * 16 + m) * 72 + quad * 8];
            const bf16x8 b0 = *(const bf16x8*)bp;
            const bf16x8 b1 = *(const bf16x8*)(bp + 32);
            acc[i] = __builtin_amdgcn_mfma_f32_16x16x32_bf16(a0.v, b0, acc[i], 0, 0, 0);
            acc[i] = __builtin_amdgcn_mfma_f32_16x16x32_bf16(a1.v, b1, acc[i], 0, 0, 0);
        }
        // flush finished blocks (C layout: col=lane&15, row=quad*4+reg)
        #pragma unroll
        for (int i = 0; i < 6; ++i) {
            const int s = 2048 >> i;
            if (((kb + 64) & (s - 1)) == 0) {
                const int j = kb >> (11 - i);
                const int offt = 16 * ((2 << i) - 2);
                u16* cp = codes + (size_t)(t0 + wv * 16 + quad * 4) * CSTRIDE
                        + offt + j * 16 + m;
                cp[0 * CSTRIDE] = f2bf(acc[i][0]);
                cp[1 * CSTRIDE] = f2bf(acc[i][1]);
                cp[2 * CSTRIDE] = f2bf(acc[i][2]);
                cp[3 * CSTRIDE] = f2bf(acc[i][3]);
                acc[i] = (f32x4){0.f, 0.f, 0.f, 0.f};
            }
        }
    }
}

// -------------------- Kernel 2: output GEMMs via MFMA -----------------------
// Grid (64, T/64). A(64x160) = [x_chunk bf16 | sibling codes], B = WT[b],
// 5 K-steps x 4 n-tiles; epilogue repacks C through LDS for float4 stores.
__global__ __launch_bounds__(256) void hodlr_out(
    const float* __restrict__ x, const u16* __restrict__ codes,
    const u16* __restrict__ WT, const float* __restrict__ bias,
    float* __restrict__ out)
{
    __shared__ __align__(16) u16 As[64 * 168];   // [row][k], stride 168 bf16
    __shared__ __align__(16) u16 Ws[64 * 168];   // [n][k]

    const int tid = threadIdx.x, lane = tid & 63, wv = tid >> 6;
    const int m = lane & 15, quad = lane >> 4;
    const int bch = blockIdx.x, t0 = blockIdx.y * 64;

    // ---- stage A: x chunk (64 rows x 64 cols), fp32->bf16
    #pragma unroll
    for (int p = 0; p < 4; ++p) {
        const int idx = tid + p * 256;            // 0..1023
        const int row = idx >> 4, c4 = idx & 15;
        const float4 xv = *(const float4*)(x + (size_t)(t0 + row) * D + bch * 64 + c4 * 4);
        u16x4v pk; pk[0] = f2bf(xv.x); pk[1] = f2bf(xv.y); pk[2] = f2bf(xv.z); pk[3] = f2bf(xv.w);
        *(u16x4v*)&As[row * 168 + c4 * 4] = pk;
    }
    // ---- stage A: sibling codes (64 rows x 6 layers x 16), raw bf16 copy
    #pragma unroll
    for (int p = 0; p < 3; ++p) {
        const int u = tid + p * 256;              // 0..767
        const int row = u / 12, rem = u - row * 12, i = rem >> 1, h = rem & 1;
        const int offt = 16 * ((2 << i) - 2);
        const int sib = (bch >> (5 - i)) ^ 1;
        *(float4*)&As[row * 168 + 64 + i * 16 + h * 8] =
            *(const float4*)(codes + (size_t)(t0 + row) * CSTRIDE + offt + sib * 16 + h * 8);
    }
    // ---- stage B: WT[b] (64 n x 160 k bf16, contiguous)
    #pragma unroll
    for (int p = 0; p < 5; ++p) {
        const int u = tid + p * 256;              // 0..1279
        const int n = u / 20, seg = u - n * 20;
        *(float4*)&Ws[n * 168 + seg * 8] =
            *(const float4*)(WT + (size_t)bch * 10240 + (size_t)u * 8);
    }
    __syncthreads();

    f32x4 acc[4];
    #pragma unroll
    for (int nt = 0; nt < 4; ++nt) acc[nt] = (f32x4){0.f, 0.f, 0.f, 0.f};

    #pragma unroll
    for (int s = 0; s < 5; ++s) {
        const bf16x8 a = *(const bf16x8*)&As[(wv * 16 + m) * 168 + s * 32 + quad * 8];
        #pragma unroll
        for (int nt = 0; nt < 4; ++nt) {
            const bf16x8 b = *(const bf16x8*)&Ws[(nt * 16 + m) * 168 + s * 32 + quad * 8];
            acc[nt] = __builtin_amdgcn_mfma_f32_16x16x32_bf16(a, b, acc[nt], 0, 0, 0);
        }
    }
    __syncthreads();   // all waves done reading As/Ws

    // ---- epilogue: repack C via LDS (reuse As as fp32 64x68), +bias, float4 out
    float* Of = (float*)As;
    #pragma unroll
    for (int nt = 0; nt < 4; ++nt)
        #pragma unroll
        for (int v = 0; v < 4; ++v)
            Of[(wv * 16 + quad * 4 + v) * 68 + nt * 16 + m] = acc[nt][v];
    __syncthreads();

    #pragma unroll
    for (int p = 0; p < 4; ++p) {
        const int u = tid + p * 256;              // 0..1023
        const int row = u >> 4, seg = u & 15;     // seg: float4 within 64 cols
        float4 val = *(const float4*)&Of[row * 68 + seg * 4];
        const float4 bv = *(const float4*)(bias + bch * 64 + seg * 4);
        val.x += bv.x; val.y += bv.y; val.z += bv.z; val.w += bv.w;
        *(float4*)(out + (size_t)(t0 + row) * D + bch * 64 + seg * 4) = val;
    }
}

// -------------------- launch ----------------------------------------------
extern "C" void kernel_launch(void* const* d_in, const int* in_sizes, int n_in,
                              void* d_out, int out_size, void* d_ws, size_t ws_size,
                              hipStream_t stream)
{
    const float* x   = (const float*)d_in[0];
    const float* us0 = (const float*)d_in[1];
    const float* vs0 = (const float*)d_in[2];
    const float* us1 = (const float*)d_in[3];
    const float* vs1 = (const float*)d_in[4];
    const float* us2 = (const float*)d_in[5];
    const float* vs2 = (const float*)d_in[6];
    const float* us3 = (const float*)d_in[7];
    const float* vs3 = (const float*)d_in[8];
    const float* us4 = (const float*)d_in[9];
    const float* vs4 = (const float*)d_in[10];
    const float* us5 = (const float*)d_in[11];
    const float* vs5 = (const float*)d_in[12];
    const float* dsm = (const float*)d_in[13];
    const float* bias= (const float*)d_in[14];
    float* out = (float*)d_out;

    const int T = in_sizes[0] / D;               // 16384 rows

    // ws layout (bf16): codes | usT | WT
    u16* codes = (u16*)d_ws;                     // T*2016
    u16* usT   = codes + (size_t)T * CSTRIDE;    // 6*65536
    u16* WTp   = usT + 6 * 65536;                // 64*10240

    hipLaunchKernelGGL(hodlr_prep, dim3((6 * 65536 + 64 * 10240) / 256), dim3(256), 0, stream,
                       us0, us1, us2, us3, us4, us5,
                       vs0, vs1, vs2, vs3, vs4, vs5, dsm, usT, WTp);
    hipLaunchKernelGGL(hodlr_codes, dim3(T / 64, 2), dim3(256), 0, stream,
                       x, usT, codes);
    hipLaunchKernelGGL(hodlr_out, dim3(64, T / 64), dim3(256), 0, stream,
                       x, codes, WTp, bias, out);
}